// Round 24
// baseline (117.468 us; speedup 1.0000x reference)
//
#include <hip/hip_runtime.h>
#include <math.h>

// RankingLoss = mean over rows of sum_{pairs: lab_a-lab_b > TOL} lsig(lg_a-lg_b)
//
// r24 DIAGNOSTIC on the r21 champion (26.64us, absmax 0.0): rank_work's body
// runs REP=8 times (idempotent: identical partials rewritten; asm memory
// clobber defeats hoisting). Purpose: (1) dur = pre + 8w + final => w =
// (dur-26.6)/7 measured directly; (2) rank_work becomes the longest dispatch
// => its VALUBusy/Occupancy/LDS-conflict counters become visible in top-5,
// identifying the regime of the ~2.5x model miss. All math/staging identical
// to r21 (packed v2f tile core, staged side windows, bucket-major pre).

#define NN 2048
#define BB 64
#define TOLF 0.01f
#define BLK 256
#define NTILE 20                         // i-tiles of 512: offsets it*(it+1)
#define TILEBLKS (BB * NTILE)            // 1280
#define SIDEBLKS (BB * 8)                // 512
#define WGRID (TILEBLKS + SIDEBLKS)      // 1792
#define SWIN 448
#define REP 8
#define LOG2E 1.4426950408889634f

typedef float v2f __attribute__((ext_vector_type(2)));

__device__ float2 g_labs[BB][NN];  // (label, s) bucket-major
__device__ float  g_Es[BB][NN];    // 2^s = e^logit
__device__ int    g_C[BB][NN];     // start of bucket b_i - 1
__device__ float  g_part[TILEBLKS];
__device__ double g_partS[SIDEBLKS];

// ---------------- preprocess: bucket reorder via LDS, coalesced export (r15) ----------------
__global__ __launch_bounds__(BLK) void rank_pre(const float* __restrict__ logits,
                                                const float* __restrict__ labels) {
    __shared__ float2 sls[NN];
    __shared__ float  sEv[NN];
    __shared__ int    sC[NN];
    __shared__ int    cnt[100], pref[101], offs[100];
    __shared__ int    wtot;
    const int row = blockIdx.x, tid = threadIdx.x;
    const float* lg = logits + (size_t)row * NN;
    const float* lb = labels + (size_t)row * NN;

    for (int x = tid; x < 100; x += BLK) { cnt[x] = 0; offs[x] = 0; }
    __syncthreads();

    int   myb[8];
    float myla[8], mylg[8];
#pragma unroll
    for (int q = 0; q < 8; ++q) {
        int x = tid + q * BLK;
        myla[q] = lb[x];
        mylg[q] = lg[x];
        myb[q]  = min(99, (int)(myla[q] * 100.0f));
        atomicAdd(&cnt[myb[q]], 1);
    }
    __syncthreads();
    {   // wave-parallel exclusive prefix over 100 counts
        int v = (tid < 100) ? cnt[tid] : 0;
        int x = v;
#pragma unroll
        for (int o = 1; o < 64; o <<= 1) {
            int y = __shfl_up(x, o);
            if ((tid & 63) >= o) x += y;
        }
        if (tid == 63) wtot = x;
        __syncthreads();
        if (tid >= 64 && tid < 128) x += wtot;
        if (tid < 101) pref[tid] = x - v;
    }
    __syncthreads();
#pragma unroll
    for (int q = 0; q < 8; ++q) {
        int b = myb[q];
        int p = pref[b] + atomicAdd(&offs[b], 1);
        float s = mylg[q] * LOG2E;
        sls[p] = make_float2(myla[q], s);
        sEv[p] = __builtin_amdgcn_exp2f(s);
        sC[p]  = (b >= 1) ? pref[b - 1] : 0;
    }
    __syncthreads();
    for (int x = tid; x < NN; x += BLK) {
        g_labs[row][x] = sls[x];
        g_Es[row][x]   = sEv[x];
        g_C[row][x]    = sC[x];
    }
}

// ---------------- main work: REP x (side + tiles), r21 math ----------------
__global__ __launch_bounds__(BLK) void rank_work() {
    const int bid = blockIdx.x;
    for (int rep = 0; rep < REP; ++rep) {
        asm volatile("" ::: "memory");           // defeat cross-rep CSE/LICM
        if (bid < SIDEBLKS) {
            __shared__ float2 sLS[SWIN];
            __shared__ float  sE[SWIN];
            __shared__ int    sCs;
            __shared__ double sdw[4];
            const int row = bid >> 3;
            const int c0  = (bid & 7) << 8;
            const int tid = threadIdx.x;
            if (tid == 0) sCs = g_C[row][c0];
            __syncthreads();
            const int Cs  = sCs;
            const int len = c0 + 256 - Cs;
            for (int x = tid; x < len; x += BLK) {
                sLS[x] = g_labs[row][Cs + x];
                sE[x]  = g_Es[row][Cs + x];
            }
            __syncthreads();

            const int i    = c0 + tid;
            const int iloc = i - Cs;
            const float2 lsi = sLS[iloc];
            const float lai = lsi.x, si = lsi.y;
            const float Ei  = sE[iloc];
            const int wloc  = g_C[row][i] - Cs;

            float accL = 0.0f, accS = 0.0f;
            float p = 1.0f;
            int cnt8 = 0;
            for (int j = wloc; j < iloc; ++j) {
                float2 ls = sLS[j];
                float ld = lai - ls.x;
                bool valid = fabsf(ld) > TOLF;   // exact reference predicate
                float term = valid ? (Ei + sE[j]) : 1.0f;
                p *= term;
                if (++cnt8 == 8) { accL += __builtin_amdgcn_logf(p); p = 1.0f; cnt8 = 0; }
                float sh = (ld > 0.0f) ? si : ls.y;
                accS -= valid ? sh : 0.0f;
            }
            accL += __builtin_amdgcn_logf(p);

            double acc = (double)accL + (double)accS;
            for (int off = 32; off > 0; off >>= 1) acc += __shfl_down(acc, off);
            if ((tid & 63) == 0) sdw[tid >> 6] = acc;
            __syncthreads();
            if (tid == 0) g_partS[bid] = sdw[0] + sdw[1] + sdw[2] + sdw[3];
            __syncthreads();
        } else {
            __shared__ __align__(16) float swin[256];
            __shared__ float swave[4];
            const int tb = bid - SIDEBLKS;
            const int row = tb / NTILE;          // block-uniform
            const int t = tb % NTILE;
            const int it = (t < 2) ? 0 : (t < 6) ? 1 : (t < 12) ? 2 : 3;
            const int jt = t - it * (it + 1);
            const int ibeg = it * 512, jbeg = jt * 256;

            float accL = 0.0f;
            const int Cmax = g_C[row][ibeg + 511];
            if (jbeg < Cmax) {
                for (int x = threadIdx.x; x < 64; x += BLK)
                    ((float4*)swin)[x] = ((const float4*)&g_Es[row][jbeg])[x];
                __syncthreads();
                const int ia = ibeg + threadIdx.x;
                const int ib = ia + 256;
                const float invEa = __builtin_amdgcn_rcpf(g_Es[row][ia]);
                const float invEb = __builtin_amdgcn_rcpf(g_Es[row][ib]);
                v2f iA; iA.x = invEa; iA.y = invEa;
                v2f iB; iB.x = invEb; iB.y = invEb;
                int tripa = max(0, min(256, g_C[row][ia] - jbeg));
                int tripb = max(0, min(256, g_C[row][ib] - jbeg));
                const int m16a = tripa & ~15;
                const int m16b = tripb & ~15;

                for (int jj = 0; jj < m16a; jj += 16) {
                    const v2f* qw = (const v2f*)&swin[jj];   // uniform b64 bcast
                    v2f a0; a0.x = 1.0f; a0.y = 1.0f;
                    v2f a1 = a0, b0 = a0, b1 = a0;
#pragma unroll
                    for (int u = 0; u < 4; ++u) {
                        v2f w = qw[u];
                        a0 = __builtin_elementwise_fma(w * iA, a0, a0);
                        b0 = __builtin_elementwise_fma(w * iB, b0, b0);
                    }
#pragma unroll
                    for (int u = 4; u < 8; ++u) {
                        v2f w = qw[u];
                        a1 = __builtin_elementwise_fma(w * iA, a1, a1);
                        b1 = __builtin_elementwise_fma(w * iB, b1, b1);
                    }
                    accL += __builtin_amdgcn_logf(a0.x * a0.y)
                          + __builtin_amdgcn_logf(a1.x * a1.y)
                          + __builtin_amdgcn_logf(b0.x * b0.y)
                          + __builtin_amdgcn_logf(b1.x * b1.y);
                }
                for (int jj = m16a; jj < m16b; jj += 16) {
                    const v2f* qw = (const v2f*)&swin[jj];
                    v2f b0; b0.x = 1.0f; b0.y = 1.0f;
                    v2f b1 = b0;
#pragma unroll
                    for (int u = 0; u < 4; ++u)
                        b0 = __builtin_elementwise_fma(qw[u] * iB, b0, b0);
#pragma unroll
                    for (int u = 4; u < 8; ++u)
                        b1 = __builtin_elementwise_fma(qw[u] * iB, b1, b1);
                    accL += __builtin_amdgcn_logf(b0.x * b0.y)
                          + __builtin_amdgcn_logf(b1.x * b1.y);
                }
                if (m16a < tripa) {
                    float p0 = 1.0f, p1 = 1.0f;
#pragma unroll
                    for (int u = 0; u < 8; ++u) {
                        float t0 = (m16a + u     < tripa) ? fmaf(swin[m16a + u],     invEa, 1.0f) : 1.0f;
                        float t1 = (m16a + 8 + u < tripa) ? fmaf(swin[m16a + 8 + u], invEa, 1.0f) : 1.0f;
                        p0 *= t0; p1 *= t1;
                    }
                    accL += __builtin_amdgcn_logf(p0) + __builtin_amdgcn_logf(p1);
                }
                if (m16b < tripb) {
                    float p0 = 1.0f, p1 = 1.0f;
#pragma unroll
                    for (int u = 0; u < 8; ++u) {
                        float t0 = (m16b + u     < tripb) ? fmaf(swin[m16b + u],     invEb, 1.0f) : 1.0f;
                        float t1 = (m16b + 8 + u < tripb) ? fmaf(swin[m16b + 8 + u], invEb, 1.0f) : 1.0f;
                        p0 *= t0; p1 *= t1;
                    }
                    accL += __builtin_amdgcn_logf(p0) + __builtin_amdgcn_logf(p1);
                }
            }
            for (int off = 32; off > 0; off >>= 1) accL += __shfl_down(accL, off);
            if ((threadIdx.x & 63) == 0) swave[threadIdx.x >> 6] = accL;
            __syncthreads();
            if (threadIdx.x == 0)
                g_part[tb] = swave[0] + swave[1] + swave[2] + swave[3];
            __syncthreads();
        }
    }
}

__global__ __launch_bounds__(BLK) void rank_final(float* __restrict__ out) {
    double acc = 0.0;
    for (int idx = threadIdx.x; idx < TILEBLKS; idx += BLK) acc += (double)g_part[idx];
    for (int idx = threadIdx.x; idx < SIDEBLKS; idx += BLK) acc += g_partS[idx];
    for (int off = 32; off > 0; off >>= 1) acc += __shfl_down(acc, off);
    __shared__ double sw[4];
    if ((threadIdx.x & 63) == 0) sw[threadIdx.x >> 6] = acc;
    __syncthreads();
    if (threadIdx.x == 0)
        out[0] = (float)((sw[0] + sw[1] + sw[2] + sw[3]) *
                         (-0.6931471805599453 / (double)BB));
}

extern "C" void kernel_launch(void* const* d_in, const int* in_sizes, int n_in,
                              void* d_out, int out_size, void* d_ws, size_t ws_size,
                              hipStream_t stream) {
    const float* logits = (const float*)d_in[0];
    const float* labels = (const float*)d_in[1];
    float* out = (float*)d_out;
    (void)in_sizes; (void)n_in; (void)out_size; (void)d_ws; (void)ws_size;

    rank_pre<<<BB, BLK, 0, stream>>>(logits, labels);
    rank_work<<<WGRID, BLK, 0, stream>>>();
    rank_final<<<1, BLK, 0, stream>>>(out);
}

// Round 25
// 59.821 us; speedup vs baseline: 1.9637x; 1.9637x over previous
//
#include <hip/hip_runtime.h>
#include <math.h>

// RankingLoss = mean over rows of sum_{pairs: lab_a-lab_b > TOL} lsig(lg_a-lg_b)
//
// r25 = r21 champion (26.64us) + two changes:
//  (1) DIAGNOSTIC: rank_pre body repeated REP=16 (idempotent; asm clobber).
//      Its dispatch time / 16 = true pre cost; counters show its regime.
//  (2) CANDIDATE: heavy-first tile order. Tiles sorted by d=2*it-jt desc
//      (dense 512-pair-per-thread tiles first, masked diagonal last),
//      rank-major across rows -> heavy blocks start at t=0, light ones pack
//      the drain tail (r24: Occupancy 33%, VALUBusy 59% = imbalance tail).
// Work math byte-identical to r21 (packed v2f core, staged side windows).

#define NN 2048
#define BB 64
#define TOLF 0.01f
#define BLK 256
#define NTILE 20
#define TILEBLKS (BB * NTILE)            // 1280
#define SIDEBLKS (BB * 8)                // 512
#define WGRID (TILEBLKS + SIDEBLKS)      // 1792
#define SWIN 448
#define PREREP 16
#define LOG2E 1.4426950408889634f

typedef float v2f __attribute__((ext_vector_type(2)));

__device__ float2 g_labs[BB][NN];  // (label, s) bucket-major
__device__ float  g_Es[BB][NN];    // 2^s = e^logit
__device__ int    g_C[BB][NN];     // start of bucket b_i - 1
__device__ float  g_part[TILEBLKS];
__device__ double g_partS[SIDEBLKS];

// heavy-first tile order: d = 2*it - jt descending
__constant__ int c_IT[NTILE] = {3,3,3,2,3,2,3,2,1,3,2,1,3,2,1,0,3,2,1,0};
__constant__ int c_JT[NTILE] = {0,1,2,0,3,1,4,2,0,5,3,1,6,4,2,0,7,5,3,1};

// ---------------- preprocess (x16 diagnostic): bucket reorder via LDS ----------------
__global__ __launch_bounds__(BLK) void rank_pre(const float* __restrict__ logits,
                                                const float* __restrict__ labels) {
    __shared__ float2 sls[NN];
    __shared__ float  sEv[NN];
    __shared__ int    sC[NN];
    __shared__ int    cnt[100], pref[101], offs[100];
    __shared__ int    wtot;
    const int row = blockIdx.x, tid = threadIdx.x;
    const float* lg = logits + (size_t)row * NN;
    const float* lb = labels + (size_t)row * NN;

    for (int rep = 0; rep < PREREP; ++rep) {
        asm volatile("" ::: "memory");   // defeat cross-rep CSE/LICM
        __syncthreads();                 // protect smem reuse across reps
        for (int x = tid; x < 100; x += BLK) { cnt[x] = 0; offs[x] = 0; }
        __syncthreads();

        int   myb[8];
        float myla[8], mylg[8];
#pragma unroll
        for (int q = 0; q < 8; ++q) {
            int x = tid + q * BLK;
            myla[q] = lb[x];
            mylg[q] = lg[x];
            myb[q]  = min(99, (int)(myla[q] * 100.0f));
            atomicAdd(&cnt[myb[q]], 1);
        }
        __syncthreads();
        {   // wave-parallel exclusive prefix over 100 counts
            int v = (tid < 100) ? cnt[tid] : 0;
            int x = v;
#pragma unroll
            for (int o = 1; o < 64; o <<= 1) {
                int y = __shfl_up(x, o);
                if ((tid & 63) >= o) x += y;
            }
            if (tid == 63) wtot = x;
            __syncthreads();
            if (tid >= 64 && tid < 128) x += wtot;
            if (tid < 101) pref[tid] = x - v;
        }
        __syncthreads();
#pragma unroll
        for (int q = 0; q < 8; ++q) {
            int b = myb[q];
            int p = pref[b] + atomicAdd(&offs[b], 1);
            float s = mylg[q] * LOG2E;
            sls[p] = make_float2(myla[q], s);
            sEv[p] = __builtin_amdgcn_exp2f(s);
            sC[p]  = (b >= 1) ? pref[b - 1] : 0;
        }
        __syncthreads();
        for (int x = tid; x < NN; x += BLK) {
            g_labs[row][x] = sls[x];
            g_Es[row][x]   = sEv[x];
            g_C[row][x]    = sC[x];
        }
    }
}

// ---------------- main work: side (first) + tiles (heavy-first order) ----------------
__global__ __launch_bounds__(BLK) void rank_work() {
    const int bid = blockIdx.x;
    if (bid < SIDEBLKS) {
        __shared__ float2 sLS[SWIN];
        __shared__ float  sE[SWIN];
        __shared__ int    sCs;
        __shared__ double sdw[4];
        const int row = bid >> 3;
        const int c0  = (bid & 7) << 8;
        const int tid = threadIdx.x;
        if (tid == 0) sCs = g_C[row][c0];
        __syncthreads();
        const int Cs  = sCs;
        const int len = c0 + 256 - Cs;
        for (int x = tid; x < len; x += BLK) {
            sLS[x] = g_labs[row][Cs + x];
            sE[x]  = g_Es[row][Cs + x];
        }
        __syncthreads();

        const int i    = c0 + tid;
        const int iloc = i - Cs;
        const float2 lsi = sLS[iloc];
        const float lai = lsi.x, si = lsi.y;
        const float Ei  = sE[iloc];
        const int wloc  = g_C[row][i] - Cs;

        float accL = 0.0f, accS = 0.0f;
        float p = 1.0f;
        int cnt8 = 0;
        for (int j = wloc; j < iloc; ++j) {
            float2 ls = sLS[j];
            float ld = lai - ls.x;
            bool valid = fabsf(ld) > TOLF;         // exact reference predicate
            float term = valid ? (Ei + sE[j]) : 1.0f;
            p *= term;
            if (++cnt8 == 8) { accL += __builtin_amdgcn_logf(p); p = 1.0f; cnt8 = 0; }
            float sh = (ld > 0.0f) ? si : ls.y;
            accS -= valid ? sh : 0.0f;
        }
        accL += __builtin_amdgcn_logf(p);

        double acc = (double)accL + (double)accS;
        for (int off = 32; off > 0; off >>= 1) acc += __shfl_down(acc, off);
        if ((tid & 63) == 0) sdw[tid >> 6] = acc;
        __syncthreads();
        if (tid == 0) g_partS[bid] = sdw[0] + sdw[1] + sdw[2] + sdw[3];
    } else {
        __shared__ __align__(16) float swin[256];
        __shared__ float swave[4];
        const int tb = bid - SIDEBLKS;
        const int rank = tb >> 6;                  // 0..19, heavy-first
        const int row  = tb & 63;
        const int it = c_IT[rank];
        const int jt = c_JT[rank];
        const int ibeg = it * 512, jbeg = jt * 256;

        float accL = 0.0f;
        const int Cmax = g_C[row][ibeg + 511];     // C monotone in position
        if (jbeg < Cmax) {
            for (int x = threadIdx.x; x < 64; x += BLK)
                ((float4*)swin)[x] = ((const float4*)&g_Es[row][jbeg])[x];
            __syncthreads();
            const int ia = ibeg + threadIdx.x;
            const int ib = ia + 256;
            const float invEa = __builtin_amdgcn_rcpf(g_Es[row][ia]);
            const float invEb = __builtin_amdgcn_rcpf(g_Es[row][ib]);
            v2f iA; iA.x = invEa; iA.y = invEa;
            v2f iB; iB.x = invEb; iB.y = invEb;
            int tripa = max(0, min(256, g_C[row][ia] - jbeg));
            int tripb = max(0, min(256, g_C[row][ib] - jbeg));   // >= tripa
            const int m16a = tripa & ~15;
            const int m16b = tripb & ~15;

            for (int jj = 0; jj < m16a; jj += 16) {
                const v2f* qw = (const v2f*)&swin[jj];   // uniform b64 broadcast
                v2f a0; a0.x = 1.0f; a0.y = 1.0f;
                v2f a1 = a0, b0 = a0, b1 = a0;
#pragma unroll
                for (int u = 0; u < 4; ++u) {
                    v2f w = qw[u];
                    a0 = __builtin_elementwise_fma(w * iA, a0, a0);
                    b0 = __builtin_elementwise_fma(w * iB, b0, b0);
                }
#pragma unroll
                for (int u = 4; u < 8; ++u) {
                    v2f w = qw[u];
                    a1 = __builtin_elementwise_fma(w * iA, a1, a1);
                    b1 = __builtin_elementwise_fma(w * iB, b1, b1);
                }
                accL += __builtin_amdgcn_logf(a0.x * a0.y)
                      + __builtin_amdgcn_logf(a1.x * a1.y)
                      + __builtin_amdgcn_logf(b0.x * b0.y)
                      + __builtin_amdgcn_logf(b1.x * b1.y);
            }
            for (int jj = m16a; jj < m16b; jj += 16) {
                const v2f* qw = (const v2f*)&swin[jj];
                v2f b0; b0.x = 1.0f; b0.y = 1.0f;
                v2f b1 = b0;
#pragma unroll
                for (int u = 0; u < 4; ++u)
                    b0 = __builtin_elementwise_fma(qw[u] * iB, b0, b0);
#pragma unroll
                for (int u = 4; u < 8; ++u)
                    b1 = __builtin_elementwise_fma(qw[u] * iB, b1, b1);
                accL += __builtin_amdgcn_logf(b0.x * b0.y)
                      + __builtin_amdgcn_logf(b1.x * b1.y);
            }
            if (m16a < tripa) {
                float p0 = 1.0f, p1 = 1.0f;
#pragma unroll
                for (int u = 0; u < 8; ++u) {
                    float t0 = (m16a + u     < tripa) ? fmaf(swin[m16a + u],     invEa, 1.0f) : 1.0f;
                    float t1 = (m16a + 8 + u < tripa) ? fmaf(swin[m16a + 8 + u], invEa, 1.0f) : 1.0f;
                    p0 *= t0; p1 *= t1;
                }
                accL += __builtin_amdgcn_logf(p0) + __builtin_amdgcn_logf(p1);
            }
            if (m16b < tripb) {
                float p0 = 1.0f, p1 = 1.0f;
#pragma unroll
                for (int u = 0; u < 8; ++u) {
                    float t0 = (m16b + u     < tripb) ? fmaf(swin[m16b + u],     invEb, 1.0f) : 1.0f;
                    float t1 = (m16b + 8 + u < tripb) ? fmaf(swin[m16b + 8 + u], invEb, 1.0f) : 1.0f;
                    p0 *= t0; p1 *= t1;
                }
                accL += __builtin_amdgcn_logf(p0) + __builtin_amdgcn_logf(p1);
            }
        }
        for (int off = 32; off > 0; off >>= 1) accL += __shfl_down(accL, off);
        if ((threadIdx.x & 63) == 0) swave[threadIdx.x >> 6] = accL;
        __syncthreads();
        if (threadIdx.x == 0)
            g_part[tb] = swave[0] + swave[1] + swave[2] + swave[3];
    }
}

__global__ __launch_bounds__(BLK) void rank_final(float* __restrict__ out) {
    double acc = 0.0;
    for (int idx = threadIdx.x; idx < TILEBLKS; idx += BLK) acc += (double)g_part[idx];
    for (int idx = threadIdx.x; idx < SIDEBLKS; idx += BLK) acc += g_partS[idx];
    for (int off = 32; off > 0; off >>= 1) acc += __shfl_down(acc, off);
    __shared__ double sw[4];
    if ((threadIdx.x & 63) == 0) sw[threadIdx.x >> 6] = acc;
    __syncthreads();
    if (threadIdx.x == 0)
        out[0] = (float)((sw[0] + sw[1] + sw[2] + sw[3]) *
                         (-0.6931471805599453 / (double)BB));
}

extern "C" void kernel_launch(void* const* d_in, const int* in_sizes, int n_in,
                              void* d_out, int out_size, void* d_ws, size_t ws_size,
                              hipStream_t stream) {
    const float* logits = (const float*)d_in[0];
    const float* labels = (const float*)d_in[1];
    float* out = (float*)d_out;
    (void)in_sizes; (void)n_in; (void)out_size; (void)d_ws; (void)ws_size;

    rank_pre<<<BB, BLK, 0, stream>>>(logits, labels);
    rank_work<<<WGRID, BLK, 0, stream>>>();
    rank_final<<<1, BLK, 0, stream>>>(out);
}

// Round 26
// 24.912 us; speedup vs baseline: 4.7154x; 2.4013x over previous
//
#include <hip/hip_runtime.h>
#include <math.h>

// RankingLoss = mean over rows of sum_{pairs: lab_a-lab_b > TOL} lsig(lg_a-lg_b)
//
// lsig(x) = -ln2*log2(1 + 2^{s_lo - s_hi}),  s = logit*log2e,  E = 2^s.
// Rows bucket-major by label (width TOL). j < C_i (C_i = start of bucket
// b_i-1) => pair valid, i = high.
//   tile core (packed v2f): t = E_j*invE_i; p = fma(t,p,p); 512i x 256j.
//   side (C_i <= j < i): exact |ld|>TOL mask; (Ei+Ej) product; accS -= s_hi.
// r26 = r25 with the PREREP=16 diagnostic reverted; keeps HEAVY-FIRST tile
// order (d = 2*it - jt descending, rank-major across rows). r25 measured:
// pre = 2.7us, heavy-first work ~16us vs ~24us light-first (r21's ascending-t
// dispatched all 512 heaviest it=3 tiles LAST -> low-residency drain tail).

#define NN 2048
#define BB 64
#define TOLF 0.01f
#define BLK 256
#define NTILE 20
#define TILEBLKS (BB * NTILE)            // 1280
#define SIDEBLKS (BB * 8)                // 512
#define WGRID (TILEBLKS + SIDEBLKS)      // 1792
#define SWIN 448
#define LOG2E 1.4426950408889634f

typedef float v2f __attribute__((ext_vector_type(2)));

__device__ float2 g_labs[BB][NN];  // (label, s) bucket-major
__device__ float  g_Es[BB][NN];    // 2^s = e^logit
__device__ int    g_C[BB][NN];     // start of bucket b_i - 1
__device__ float  g_part[TILEBLKS];
__device__ double g_partS[SIDEBLKS];

// heavy-first tile order: d = 2*it - jt descending
__constant__ int c_IT[NTILE] = {3,3,3,2,3,2,3,2,1,3,2,1,3,2,1,0,3,2,1,0};
__constant__ int c_JT[NTILE] = {0,1,2,0,3,1,4,2,0,5,3,1,6,4,2,0,7,5,3,1};

// ---------------- preprocess: bucket reorder via LDS, coalesced export ----------------
__global__ __launch_bounds__(BLK) void rank_pre(const float* __restrict__ logits,
                                                const float* __restrict__ labels) {
    __shared__ float2 sls[NN];
    __shared__ float  sEv[NN];
    __shared__ int    sC[NN];
    __shared__ int    cnt[100], pref[101], offs[100];
    __shared__ int    wtot;
    const int row = blockIdx.x, tid = threadIdx.x;
    const float* lg = logits + (size_t)row * NN;
    const float* lb = labels + (size_t)row * NN;

    for (int x = tid; x < 100; x += BLK) { cnt[x] = 0; offs[x] = 0; }
    __syncthreads();

    int   myb[8];
    float myla[8], mylg[8];
#pragma unroll
    for (int q = 0; q < 8; ++q) {
        int x = tid + q * BLK;
        myla[q] = lb[x];
        mylg[q] = lg[x];
        myb[q]  = min(99, (int)(myla[q] * 100.0f));
        atomicAdd(&cnt[myb[q]], 1);
    }
    __syncthreads();
    {   // wave-parallel exclusive prefix over 100 counts
        int v = (tid < 100) ? cnt[tid] : 0;
        int x = v;
#pragma unroll
        for (int o = 1; o < 64; o <<= 1) {
            int y = __shfl_up(x, o);
            if ((tid & 63) >= o) x += y;
        }
        if (tid == 63) wtot = x;
        __syncthreads();
        if (tid >= 64 && tid < 128) x += wtot;
        if (tid < 101) pref[tid] = x - v;
    }
    __syncthreads();
#pragma unroll
    for (int q = 0; q < 8; ++q) {
        int b = myb[q];
        int p = pref[b] + atomicAdd(&offs[b], 1);
        float s = mylg[q] * LOG2E;
        sls[p] = make_float2(myla[q], s);
        sEv[p] = __builtin_amdgcn_exp2f(s);
        sC[p]  = (b >= 1) ? pref[b - 1] : 0;
    }
    __syncthreads();
    for (int x = tid; x < NN; x += BLK) {
        g_labs[row][x] = sls[x];
        g_Es[row][x]   = sEv[x];
        g_C[row][x]    = sC[x];
    }
}

// ---------------- main work: side (first) + tiles (heavy-first order) ----------------
__global__ __launch_bounds__(BLK) void rank_work() {
    const int bid = blockIdx.x;
    if (bid < SIDEBLKS) {
        __shared__ float2 sLS[SWIN];
        __shared__ float  sE[SWIN];
        __shared__ int    sCs;
        __shared__ double sdw[4];
        const int row = bid >> 3;
        const int c0  = (bid & 7) << 8;
        const int tid = threadIdx.x;
        if (tid == 0) sCs = g_C[row][c0];
        __syncthreads();
        const int Cs  = sCs;
        const int len = c0 + 256 - Cs;
        for (int x = tid; x < len; x += BLK) {
            sLS[x] = g_labs[row][Cs + x];
            sE[x]  = g_Es[row][Cs + x];
        }
        __syncthreads();

        const int i    = c0 + tid;
        const int iloc = i - Cs;
        const float2 lsi = sLS[iloc];
        const float lai = lsi.x, si = lsi.y;
        const float Ei  = sE[iloc];
        const int wloc  = g_C[row][i] - Cs;

        float accL = 0.0f, accS = 0.0f;
        float p = 1.0f;
        int cnt8 = 0;
        for (int j = wloc; j < iloc; ++j) {
            float2 ls = sLS[j];
            float ld = lai - ls.x;
            bool valid = fabsf(ld) > TOLF;         // exact reference predicate
            float term = valid ? (Ei + sE[j]) : 1.0f;
            p *= term;
            if (++cnt8 == 8) { accL += __builtin_amdgcn_logf(p); p = 1.0f; cnt8 = 0; }
            float sh = (ld > 0.0f) ? si : ls.y;
            accS -= valid ? sh : 0.0f;
        }
        accL += __builtin_amdgcn_logf(p);

        double acc = (double)accL + (double)accS;
        for (int off = 32; off > 0; off >>= 1) acc += __shfl_down(acc, off);
        if ((tid & 63) == 0) sdw[tid >> 6] = acc;
        __syncthreads();
        if (tid == 0) g_partS[bid] = sdw[0] + sdw[1] + sdw[2] + sdw[3];
    } else {
        __shared__ __align__(16) float swin[256];
        __shared__ float swave[4];
        const int tb = bid - SIDEBLKS;
        const int rank = tb >> 6;                  // 0..19, heavy-first
        const int row  = tb & 63;
        const int it = c_IT[rank];
        const int jt = c_JT[rank];
        const int ibeg = it * 512, jbeg = jt * 256;

        float accL = 0.0f;
        const int Cmax = g_C[row][ibeg + 511];     // C monotone in position
        if (jbeg < Cmax) {
            for (int x = threadIdx.x; x < 64; x += BLK)
                ((float4*)swin)[x] = ((const float4*)&g_Es[row][jbeg])[x];
            __syncthreads();
            const int ia = ibeg + threadIdx.x;
            const int ib = ia + 256;
            const float invEa = __builtin_amdgcn_rcpf(g_Es[row][ia]);
            const float invEb = __builtin_amdgcn_rcpf(g_Es[row][ib]);
            v2f iA; iA.x = invEa; iA.y = invEa;
            v2f iB; iB.x = invEb; iB.y = invEb;
            int tripa = max(0, min(256, g_C[row][ia] - jbeg));
            int tripb = max(0, min(256, g_C[row][ib] - jbeg));   // >= tripa
            const int m16a = tripa & ~15;
            const int m16b = tripb & ~15;

            for (int jj = 0; jj < m16a; jj += 16) {
                const v2f* qw = (const v2f*)&swin[jj];   // uniform b64 broadcast
                v2f a0; a0.x = 1.0f; a0.y = 1.0f;
                v2f a1 = a0, b0 = a0, b1 = a0;
#pragma unroll
                for (int u = 0; u < 4; ++u) {
                    v2f w = qw[u];
                    a0 = __builtin_elementwise_fma(w * iA, a0, a0);
                    b0 = __builtin_elementwise_fma(w * iB, b0, b0);
                }
#pragma unroll
                for (int u = 4; u < 8; ++u) {
                    v2f w = qw[u];
                    a1 = __builtin_elementwise_fma(w * iA, a1, a1);
                    b1 = __builtin_elementwise_fma(w * iB, b1, b1);
                }
                accL += __builtin_amdgcn_logf(a0.x * a0.y)
                      + __builtin_amdgcn_logf(a1.x * a1.y)
                      + __builtin_amdgcn_logf(b0.x * b0.y)
                      + __builtin_amdgcn_logf(b1.x * b1.y);
            }
            for (int jj = m16a; jj < m16b; jj += 16) {
                const v2f* qw = (const v2f*)&swin[jj];
                v2f b0; b0.x = 1.0f; b0.y = 1.0f;
                v2f b1 = b0;
#pragma unroll
                for (int u = 0; u < 4; ++u)
                    b0 = __builtin_elementwise_fma(qw[u] * iB, b0, b0);
#pragma unroll
                for (int u = 4; u < 8; ++u)
                    b1 = __builtin_elementwise_fma(qw[u] * iB, b1, b1);
                accL += __builtin_amdgcn_logf(b0.x * b0.y)
                      + __builtin_amdgcn_logf(b1.x * b1.y);
            }
            if (m16a < tripa) {
                float p0 = 1.0f, p1 = 1.0f;
#pragma unroll
                for (int u = 0; u < 8; ++u) {
                    float t0 = (m16a + u     < tripa) ? fmaf(swin[m16a + u],     invEa, 1.0f) : 1.0f;
                    float t1 = (m16a + 8 + u < tripa) ? fmaf(swin[m16a + 8 + u], invEa, 1.0f) : 1.0f;
                    p0 *= t0; p1 *= t1;
                }
                accL += __builtin_amdgcn_logf(p0) + __builtin_amdgcn_logf(p1);
            }
            if (m16b < tripb) {
                float p0 = 1.0f, p1 = 1.0f;
#pragma unroll
                for (int u = 0; u < 8; ++u) {
                    float t0 = (m16b + u     < tripb) ? fmaf(swin[m16b + u],     invEb, 1.0f) : 1.0f;
                    float t1 = (m16b + 8 + u < tripb) ? fmaf(swin[m16b + 8 + u], invEb, 1.0f) : 1.0f;
                    p0 *= t0; p1 *= t1;
                }
                accL += __builtin_amdgcn_logf(p0) + __builtin_amdgcn_logf(p1);
            }
        }
        for (int off = 32; off > 0; off >>= 1) accL += __shfl_down(accL, off);
        if ((threadIdx.x & 63) == 0) swave[threadIdx.x >> 6] = accL;
        __syncthreads();
        if (threadIdx.x == 0)
            g_part[tb] = swave[0] + swave[1] + swave[2] + swave[3];
    }
}

__global__ __launch_bounds__(BLK) void rank_final(float* __restrict__ out) {
    double acc = 0.0;
    for (int idx = threadIdx.x; idx < TILEBLKS; idx += BLK) acc += (double)g_part[idx];
    for (int idx = threadIdx.x; idx < SIDEBLKS; idx += BLK) acc += g_partS[idx];
    for (int off = 32; off > 0; off >>= 1) acc += __shfl_down(acc, off);
    __shared__ double sw[4];
    if ((threadIdx.x & 63) == 0) sw[threadIdx.x >> 6] = acc;
    __syncthreads();
    if (threadIdx.x == 0)
        out[0] = (float)((sw[0] + sw[1] + sw[2] + sw[3]) *
                         (-0.6931471805599453 / (double)BB));
}

extern "C" void kernel_launch(void* const* d_in, const int* in_sizes, int n_in,
                              void* d_out, int out_size, void* d_ws, size_t ws_size,
                              hipStream_t stream) {
    const float* logits = (const float*)d_in[0];
    const float* labels = (const float*)d_in[1];
    float* out = (float*)d_out;
    (void)in_sizes; (void)n_in; (void)out_size; (void)d_ws; (void)ws_size;

    rank_pre<<<BB, BLK, 0, stream>>>(logits, labels);
    rank_work<<<WGRID, BLK, 0, stream>>>();
    rank_final<<<1, BLK, 0, stream>>>(out);
}

// Round 27
// 24.492 us; speedup vs baseline: 4.7961x; 1.0171x over previous
//
#include <hip/hip_runtime.h>
#include <math.h>

// RankingLoss = mean over rows of sum_{pairs: lab_a-lab_b > TOL} lsig(lg_a-lg_b)
//
// lsig(x) = -ln2*log2(1 + 2^{s_lo - s_hi}),  s = logit*log2e,  E = 2^s.
// Rows bucket-major by label (width TOL). j < C_i => valid, i = high.
//   tile core (packed v2f): t = E_j*invE_i; p = fma(t,p,p); 512i x 256j,
//   HEAVY-FIRST order (r26, 24.9us champion).
// r27 change (single variable): break the cold-start dependent-miss chain.
//   r24/r25 REP experiments: work pass = 21.7us cold vs 13us warm (~8.7us
//   first-touch). Cause: global loads serialized behind the Cmax branch /
//   Cs load (3-4 deep chain x ~600cy cross-kernel cold misses).
//   Fix: issue ALL global loads unconditionally and independently up-front
//   (tiles: window+Ea/Eb/Ca/Cb/Cmax before the branch; side: conservative
//   window [c0-192, c0+256) staged in parallel with Cs/Ci loads, guarded
//   global fallback if the window is deeper than 192 — same set, same order).

#define NN 2048
#define BB 64
#define TOLF 0.01f
#define BLK 256
#define NTILE 20
#define TILEBLKS (BB * NTILE)            // 1280
#define SIDEBLKS (BB * 8)                // 512
#define WGRID (TILEBLKS + SIDEBLKS)      // 1792
#define SWIN 448
#define LOG2E 1.4426950408889634f

typedef float v2f __attribute__((ext_vector_type(2)));

__device__ float2 g_labs[BB][NN];  // (label, s) bucket-major
__device__ float  g_Es[BB][NN];    // 2^s = e^logit
__device__ int    g_C[BB][NN];     // start of bucket b_i - 1
__device__ float  g_part[TILEBLKS];
__device__ double g_partS[SIDEBLKS];

// heavy-first tile order: d = 2*it - jt descending
__constant__ int c_IT[NTILE] = {3,3,3,2,3,2,3,2,1,3,2,1,3,2,1,0,3,2,1,0};
__constant__ int c_JT[NTILE] = {0,1,2,0,3,1,4,2,0,5,3,1,6,4,2,0,7,5,3,1};

// ---------------- preprocess: bucket reorder via LDS, coalesced export ----------------
__global__ __launch_bounds__(BLK) void rank_pre(const float* __restrict__ logits,
                                                const float* __restrict__ labels) {
    __shared__ float2 sls[NN];
    __shared__ float  sEv[NN];
    __shared__ int    sC[NN];
    __shared__ int    cnt[100], pref[101], offs[100];
    __shared__ int    wtot;
    const int row = blockIdx.x, tid = threadIdx.x;
    const float* lg = logits + (size_t)row * NN;
    const float* lb = labels + (size_t)row * NN;

    for (int x = tid; x < 100; x += BLK) { cnt[x] = 0; offs[x] = 0; }
    __syncthreads();

    int   myb[8];
    float myla[8], mylg[8];
#pragma unroll
    for (int q = 0; q < 8; ++q) {
        int x = tid + q * BLK;
        myla[q] = lb[x];
        mylg[q] = lg[x];
        myb[q]  = min(99, (int)(myla[q] * 100.0f));
        atomicAdd(&cnt[myb[q]], 1);
    }
    __syncthreads();
    {   // wave-parallel exclusive prefix over 100 counts
        int v = (tid < 100) ? cnt[tid] : 0;
        int x = v;
#pragma unroll
        for (int o = 1; o < 64; o <<= 1) {
            int y = __shfl_up(x, o);
            if ((tid & 63) >= o) x += y;
        }
        if (tid == 63) wtot = x;
        __syncthreads();
        if (tid >= 64 && tid < 128) x += wtot;
        if (tid < 101) pref[tid] = x - v;
    }
    __syncthreads();
#pragma unroll
    for (int q = 0; q < 8; ++q) {
        int b = myb[q];
        int p = pref[b] + atomicAdd(&offs[b], 1);
        float s = mylg[q] * LOG2E;
        sls[p] = make_float2(myla[q], s);
        sEv[p] = __builtin_amdgcn_exp2f(s);
        sC[p]  = (b >= 1) ? pref[b - 1] : 0;
    }
    __syncthreads();
    for (int x = tid; x < NN; x += BLK) {
        g_labs[row][x] = sls[x];
        g_Es[row][x]   = sEv[x];
        g_C[row][x]    = sC[x];
    }
}

// ---------------- main work: side (first) + tiles (heavy-first order) ----------------
__global__ __launch_bounds__(BLK) void rank_work() {
    const int bid = blockIdx.x;
    const int tid = threadIdx.x;
    if (bid < SIDEBLKS) {
        // ---- side: all loads issued up-front; conservative staged window ----
        __shared__ float2 sLS[SWIN];
        __shared__ float  sE[SWIN];
        __shared__ double sdw[4];
        const int row = bid >> 3;
        const int c0  = (bid & 7) << 8;
        const int lo0 = max(0, c0 - 192);          // conservative window start
        const int wlen = c0 + 256 - lo0;           // <= 448

        // unconditional, mutually independent global loads
        const int i = c0 + tid;
        const float2 lsi = g_labs[row][i];
        const float  Ei  = g_Es[row][i];
        const int    Ci  = g_C[row][i];
        const int    Cs  = g_C[row][c0];           // broadcast (uniform addr)
        for (int x = tid; x < wlen; x += BLK) {
            sLS[x] = g_labs[row][lo0 + x];
            sE[x]  = g_Es[row][lo0 + x];
        }
        __syncthreads();

        const float lai = lsi.x, si = lsi.y;
        float accL = 0.0f, accS = 0.0f;
        float p = 1.0f;
        int cnt8 = 0;
        if (Cs >= lo0) {
            // common path: whole window is staged
            const int iloc = i - lo0;
            for (int j = Ci - lo0; j < iloc; ++j) {
                float2 ls = sLS[j];
                float ld = lai - ls.x;
                bool valid = fabsf(ld) > TOLF;     // exact reference predicate
                float term = valid ? (Ei + sE[j]) : 1.0f;
                p *= term;
                if (++cnt8 == 8) { accL += __builtin_amdgcn_logf(p); p = 1.0f; cnt8 = 0; }
                float sh = (ld > 0.0f) ? si : ls.y;
                accS -= valid ? sh : 0.0f;
            }
        } else {
            // rare fallback: window deeper than 192 -> direct global reads
            for (int j = Ci; j < i; ++j) {
                float2 ls = g_labs[row][j];
                float ld = lai - ls.x;
                bool valid = fabsf(ld) > TOLF;
                float term = valid ? (Ei + g_Es[row][j]) : 1.0f;
                p *= term;
                if (++cnt8 == 8) { accL += __builtin_amdgcn_logf(p); p = 1.0f; cnt8 = 0; }
                float sh = (ld > 0.0f) ? si : ls.y;
                accS -= valid ? sh : 0.0f;
            }
        }
        accL += __builtin_amdgcn_logf(p);

        double acc = (double)accL + (double)accS;
        for (int off = 32; off > 0; off >>= 1) acc += __shfl_down(acc, off);
        if ((tid & 63) == 0) sdw[tid >> 6] = acc;
        __syncthreads();
        if (tid == 0) g_partS[bid] = sdw[0] + sdw[1] + sdw[2] + sdw[3];
    } else {
        // ---- tiles: all loads up-front (depth-1 miss chain), packed core ----
        __shared__ __align__(16) float swin[256];
        __shared__ float swave[4];
        const int tb = bid - SIDEBLKS;
        const int rank = tb >> 6;                  // 0..19, heavy-first
        const int row  = tb & 63;
        const int it = c_IT[rank];
        const int jt = c_JT[rank];
        const int ibeg = it * 512, jbeg = jt * 256;

        // unconditional, mutually independent global loads
        const int ia = ibeg + tid;
        const int ib = ia + 256;
        const float Ea = g_Es[row][ia];
        const float Eb = g_Es[row][ib];
        const int   Ca = g_C[row][ia];
        const int   Cb = g_C[row][ib];
        const int   Cmax = g_C[row][ibeg + 511];   // C monotone in position
        if (tid < 64)
            ((float4*)swin)[tid] = ((const float4*)&g_Es[row][jbeg])[tid];
        __syncthreads();

        float accL = 0.0f;
        if (jbeg < Cmax) {
            const float invEa = __builtin_amdgcn_rcpf(Ea);
            const float invEb = __builtin_amdgcn_rcpf(Eb);
            v2f iA; iA.x = invEa; iA.y = invEa;
            v2f iB; iB.x = invEb; iB.y = invEb;
            int tripa = max(0, min(256, Ca - jbeg));
            int tripb = max(0, min(256, Cb - jbeg));   // >= tripa
            const int m16a = tripa & ~15;
            const int m16b = tripb & ~15;

            for (int jj = 0; jj < m16a; jj += 16) {
                const v2f* qw = (const v2f*)&swin[jj];   // uniform b64 broadcast
                v2f a0; a0.x = 1.0f; a0.y = 1.0f;
                v2f a1 = a0, b0 = a0, b1 = a0;
#pragma unroll
                for (int u = 0; u < 4; ++u) {
                    v2f w = qw[u];
                    a0 = __builtin_elementwise_fma(w * iA, a0, a0);
                    b0 = __builtin_elementwise_fma(w * iB, b0, b0);
                }
#pragma unroll
                for (int u = 4; u < 8; ++u) {
                    v2f w = qw[u];
                    a1 = __builtin_elementwise_fma(w * iA, a1, a1);
                    b1 = __builtin_elementwise_fma(w * iB, b1, b1);
                }
                accL += __builtin_amdgcn_logf(a0.x * a0.y)
                      + __builtin_amdgcn_logf(a1.x * a1.y)
                      + __builtin_amdgcn_logf(b0.x * b0.y)
                      + __builtin_amdgcn_logf(b1.x * b1.y);
            }
            for (int jj = m16a; jj < m16b; jj += 16) {
                const v2f* qw = (const v2f*)&swin[jj];
                v2f b0; b0.x = 1.0f; b0.y = 1.0f;
                v2f b1 = b0;
#pragma unroll
                for (int u = 0; u < 4; ++u)
                    b0 = __builtin_elementwise_fma(qw[u] * iB, b0, b0);
#pragma unroll
                for (int u = 4; u < 8; ++u)
                    b1 = __builtin_elementwise_fma(qw[u] * iB, b1, b1);
                accL += __builtin_amdgcn_logf(b0.x * b0.y)
                      + __builtin_amdgcn_logf(b1.x * b1.y);
            }
            if (m16a < tripa) {
                float p0 = 1.0f, p1 = 1.0f;
#pragma unroll
                for (int u = 0; u < 8; ++u) {
                    float t0 = (m16a + u     < tripa) ? fmaf(swin[m16a + u],     invEa, 1.0f) : 1.0f;
                    float t1 = (m16a + 8 + u < tripa) ? fmaf(swin[m16a + 8 + u], invEa, 1.0f) : 1.0f;
                    p0 *= t0; p1 *= t1;
                }
                accL += __builtin_amdgcn_logf(p0) + __builtin_amdgcn_logf(p1);
            }
            if (m16b < tripb) {
                float p0 = 1.0f, p1 = 1.0f;
#pragma unroll
                for (int u = 0; u < 8; ++u) {
                    float t0 = (m16b + u     < tripb) ? fmaf(swin[m16b + u],     invEb, 1.0f) : 1.0f;
                    float t1 = (m16b + 8 + u < tripb) ? fmaf(swin[m16b + 8 + u], invEb, 1.0f) : 1.0f;
                    p0 *= t0; p1 *= t1;
                }
                accL += __builtin_amdgcn_logf(p0) + __builtin_amdgcn_logf(p1);
            }
        }
        for (int off = 32; off > 0; off >>= 1) accL += __shfl_down(accL, off);
        if ((tid & 63) == 0) swave[tid >> 6] = accL;
        __syncthreads();
        if (tid == 0)
            g_part[tb] = swave[0] + swave[1] + swave[2] + swave[3];
    }
}

__global__ __launch_bounds__(BLK) void rank_final(float* __restrict__ out) {
    double acc = 0.0;
    for (int idx = threadIdx.x; idx < TILEBLKS; idx += BLK) acc += (double)g_part[idx];
    for (int idx = threadIdx.x; idx < SIDEBLKS; idx += BLK) acc += g_partS[idx];
    for (int off = 32; off > 0; off >>= 1) acc += __shfl_down(acc, off);
    __shared__ double sw[4];
    if ((threadIdx.x & 63) == 0) sw[threadIdx.x >> 6] = acc;
    __syncthreads();
    if (threadIdx.x == 0)
        out[0] = (float)((sw[0] + sw[1] + sw[2] + sw[3]) *
                         (-0.6931471805599453 / (double)BB));
}

extern "C" void kernel_launch(void* const* d_in, const int* in_sizes, int n_in,
                              void* d_out, int out_size, void* d_ws, size_t ws_size,
                              hipStream_t stream) {
    const float* logits = (const float*)d_in[0];
    const float* labels = (const float*)d_in[1];
    float* out = (float*)d_out;
    (void)in_sizes; (void)n_in; (void)out_size; (void)d_ws; (void)ws_size;

    rank_pre<<<BB, BLK, 0, stream>>>(logits, labels);
    rank_work<<<WGRID, BLK, 0, stream>>>();
    rank_final<<<1, BLK, 0, stream>>>(out);
}

// Round 28
// 24.210 us; speedup vs baseline: 4.8519x; 1.0116x over previous
//
#include <hip/hip_runtime.h>
#include <math.h>

// RankingLoss = mean over rows of sum_{pairs: lab_a-lab_b > TOL} lsig(lg_a-lg_b)
//
// lsig(x) = -ln2*log2(1 + 2^{s_lo - s_hi}),  s = logit*log2e,  E = 2^s.
// Rows bucket-major by label (width TOL). j < C_i => valid, i = high.
//   tile core (packed v2f): t = E_j*invE_i; p = fma(t,p,p); 512i x 256j.
// r28 change (single variable vs r27, 24.49us): XCD-AFFINE work placement.
//   Pre block r writes row r's 20KB into XCD (r%8)'s private L2 (bid->XCD
//   assumed round-robin). r27 spread each row's 28 work blocks across all 8
//   XCDs -> 7/8 of cold reads cross the die (L3), duplicating ~10MB into 8
//   L2s — the measured 8us cold-vs-warm work gap (21 vs 13, r24/r25).
//   Fix: bid%8 == row%8. Each XCD: 8 rows x 28 items = 224 blocks = 32CU x 7.
//   Within-XCD order: side items first, then HEAVY-FIRST tiles (r26 win).
//   Pure index permutation — identical math, grouping, partials.

#define NN 2048
#define BB 64
#define TOLF 0.01f
#define BLK 256
#define NTILE 20
#define TILEBLKS (BB * NTILE)            // 1280
#define SIDEBLKS (BB * 8)                // 512
#define WGRID (TILEBLKS + SIDEBLKS)      // 1792
#define SWIN 448
#define LOG2E 1.4426950408889634f

typedef float v2f __attribute__((ext_vector_type(2)));

__device__ float2 g_labs[BB][NN];  // (label, s) bucket-major
__device__ float  g_Es[BB][NN];    // 2^s = e^logit
__device__ int    g_C[BB][NN];     // start of bucket b_i - 1
__device__ float  g_part[TILEBLKS];
__device__ double g_partS[SIDEBLKS];

// heavy-first tile order: d = 2*it - jt descending
__constant__ int c_IT[NTILE] = {3,3,3,2,3,2,3,2,1,3,2,1,3,2,1,0,3,2,1,0};
__constant__ int c_JT[NTILE] = {0,1,2,0,3,1,4,2,0,5,3,1,6,4,2,0,7,5,3,1};

// ---------------- preprocess: bucket reorder via LDS, coalesced export ----------------
__global__ __launch_bounds__(BLK) void rank_pre(const float* __restrict__ logits,
                                                const float* __restrict__ labels) {
    __shared__ float2 sls[NN];
    __shared__ float  sEv[NN];
    __shared__ int    sC[NN];
    __shared__ int    cnt[100], pref[101], offs[100];
    __shared__ int    wtot;
    const int row = blockIdx.x, tid = threadIdx.x;
    const float* lg = logits + (size_t)row * NN;
    const float* lb = labels + (size_t)row * NN;

    for (int x = tid; x < 100; x += BLK) { cnt[x] = 0; offs[x] = 0; }
    __syncthreads();

    int   myb[8];
    float myla[8], mylg[8];
#pragma unroll
    for (int q = 0; q < 8; ++q) {
        int x = tid + q * BLK;
        myla[q] = lb[x];
        mylg[q] = lg[x];
        myb[q]  = min(99, (int)(myla[q] * 100.0f));
        atomicAdd(&cnt[myb[q]], 1);
    }
    __syncthreads();
    {   // wave-parallel exclusive prefix over 100 counts
        int v = (tid < 100) ? cnt[tid] : 0;
        int x = v;
#pragma unroll
        for (int o = 1; o < 64; o <<= 1) {
            int y = __shfl_up(x, o);
            if ((tid & 63) >= o) x += y;
        }
        if (tid == 63) wtot = x;
        __syncthreads();
        if (tid >= 64 && tid < 128) x += wtot;
        if (tid < 101) pref[tid] = x - v;
    }
    __syncthreads();
#pragma unroll
    for (int q = 0; q < 8; ++q) {
        int b = myb[q];
        int p = pref[b] + atomicAdd(&offs[b], 1);
        float s = mylg[q] * LOG2E;
        sls[p] = make_float2(myla[q], s);
        sEv[p] = __builtin_amdgcn_exp2f(s);
        sC[p]  = (b >= 1) ? pref[b - 1] : 0;
    }
    __syncthreads();
    for (int x = tid; x < NN; x += BLK) {
        g_labs[row][x] = sls[x];
        g_Es[row][x]   = sEv[x];
        g_C[row][x]    = sC[x];
    }
}

// ---------------- main work: XCD-affine (bid%8 == row%8), side then heavy tiles ----------------
__global__ __launch_bounds__(BLK) void rank_work() {
    const int bid = blockIdx.x;
    const int tid = threadIdx.x;
    const int xcd = bid & 7;                       // target XCD lane
    const int k   = bid >> 3;                      // 0..223 within XCD

    if (k < 64) {
        // ---- side item: row = xcd + 8*(k&7), chunk = k>>3 ----
        __shared__ float2 sLS[SWIN];
        __shared__ float  sE[SWIN];
        __shared__ double sdw[4];
        const int row = xcd + ((k & 7) << 3);
        const int chunk = k >> 3;                  // 0..7
        const int c0  = chunk << 8;
        const int lo0 = max(0, c0 - 192);
        const int wlen = c0 + 256 - lo0;           // <= 448

        const int i = c0 + tid;
        const float2 lsi = g_labs[row][i];
        const float  Ei  = g_Es[row][i];
        const int    Ci  = g_C[row][i];
        const int    Cs  = g_C[row][c0];
        for (int x = tid; x < wlen; x += BLK) {
            sLS[x] = g_labs[row][lo0 + x];
            sE[x]  = g_Es[row][lo0 + x];
        }
        __syncthreads();

        const float lai = lsi.x, si = lsi.y;
        float accL = 0.0f, accS = 0.0f;
        float p = 1.0f;
        int cnt8 = 0;
        if (Cs >= lo0) {
            const int iloc = i - lo0;
            for (int j = Ci - lo0; j < iloc; ++j) {
                float2 ls = sLS[j];
                float ld = lai - ls.x;
                bool valid = fabsf(ld) > TOLF;     // exact reference predicate
                float term = valid ? (Ei + sE[j]) : 1.0f;
                p *= term;
                if (++cnt8 == 8) { accL += __builtin_amdgcn_logf(p); p = 1.0f; cnt8 = 0; }
                float sh = (ld > 0.0f) ? si : ls.y;
                accS -= valid ? sh : 0.0f;
            }
        } else {
            for (int j = Ci; j < i; ++j) {
                float2 ls = g_labs[row][j];
                float ld = lai - ls.x;
                bool valid = fabsf(ld) > TOLF;
                float term = valid ? (Ei + g_Es[row][j]) : 1.0f;
                p *= term;
                if (++cnt8 == 8) { accL += __builtin_amdgcn_logf(p); p = 1.0f; cnt8 = 0; }
                float sh = (ld > 0.0f) ? si : ls.y;
                accS -= valid ? sh : 0.0f;
            }
        }
        accL += __builtin_amdgcn_logf(p);

        double acc = (double)accL + (double)accS;
        for (int off = 32; off > 0; off >>= 1) acc += __shfl_down(acc, off);
        if ((tid & 63) == 0) sdw[tid >> 6] = acc;
        __syncthreads();
        if (tid == 0) g_partS[(row << 3) + chunk] = sdw[0] + sdw[1] + sdw[2] + sdw[3];
    } else {
        // ---- tile item: rank = (k-64)>>3 (heavy-first), row = xcd + 8*((k-64)&7) ----
        __shared__ __align__(16) float swin[256];
        __shared__ float swave[4];
        const int kk = k - 64;                     // 0..159
        const int rank = kk >> 3;                  // 0..19
        const int row  = xcd + ((kk & 7) << 3);
        const int it = c_IT[rank];
        const int jt = c_JT[rank];
        const int ibeg = it * 512, jbeg = jt * 256;

        const int ia = ibeg + tid;
        const int ib = ia + 256;
        const float Ea = g_Es[row][ia];
        const float Eb = g_Es[row][ib];
        const int   Ca = g_C[row][ia];
        const int   Cb = g_C[row][ib];
        const int   Cmax = g_C[row][ibeg + 511];   // C monotone in position
        if (tid < 64)
            ((float4*)swin)[tid] = ((const float4*)&g_Es[row][jbeg])[tid];
        __syncthreads();

        float accL = 0.0f;
        if (jbeg < Cmax) {
            const float invEa = __builtin_amdgcn_rcpf(Ea);
            const float invEb = __builtin_amdgcn_rcpf(Eb);
            v2f iA; iA.x = invEa; iA.y = invEa;
            v2f iB; iB.x = invEb; iB.y = invEb;
            int tripa = max(0, min(256, Ca - jbeg));
            int tripb = max(0, min(256, Cb - jbeg));   // >= tripa
            const int m16a = tripa & ~15;
            const int m16b = tripb & ~15;

            for (int jj = 0; jj < m16a; jj += 16) {
                const v2f* qw = (const v2f*)&swin[jj];   // uniform b64 broadcast
                v2f a0; a0.x = 1.0f; a0.y = 1.0f;
                v2f a1 = a0, b0 = a0, b1 = a0;
#pragma unroll
                for (int u = 0; u < 4; ++u) {
                    v2f w = qw[u];
                    a0 = __builtin_elementwise_fma(w * iA, a0, a0);
                    b0 = __builtin_elementwise_fma(w * iB, b0, b0);
                }
#pragma unroll
                for (int u = 4; u < 8; ++u) {
                    v2f w = qw[u];
                    a1 = __builtin_elementwise_fma(w * iA, a1, a1);
                    b1 = __builtin_elementwise_fma(w * iB, b1, b1);
                }
                accL += __builtin_amdgcn_logf(a0.x * a0.y)
                      + __builtin_amdgcn_logf(a1.x * a1.y)
                      + __builtin_amdgcn_logf(b0.x * b0.y)
                      + __builtin_amdgcn_logf(b1.x * b1.y);
            }
            for (int jj = m16a; jj < m16b; jj += 16) {
                const v2f* qw = (const v2f*)&swin[jj];
                v2f b0; b0.x = 1.0f; b0.y = 1.0f;
                v2f b1 = b0;
#pragma unroll
                for (int u = 0; u < 4; ++u)
                    b0 = __builtin_elementwise_fma(qw[u] * iB, b0, b0);
#pragma unroll
                for (int u = 4; u < 8; ++u)
                    b1 = __builtin_elementwise_fma(qw[u] * iB, b1, b1);
                accL += __builtin_amdgcn_logf(b0.x * b0.y)
                      + __builtin_amdgcn_logf(b1.x * b1.y);
            }
            if (m16a < tripa) {
                float p0 = 1.0f, p1 = 1.0f;
#pragma unroll
                for (int u = 0; u < 8; ++u) {
                    float t0 = (m16a + u     < tripa) ? fmaf(swin[m16a + u],     invEa, 1.0f) : 1.0f;
                    float t1 = (m16a + 8 + u < tripa) ? fmaf(swin[m16a + 8 + u], invEa, 1.0f) : 1.0f;
                    p0 *= t0; p1 *= t1;
                }
                accL += __builtin_amdgcn_logf(p0) + __builtin_amdgcn_logf(p1);
            }
            if (m16b < tripb) {
                float p0 = 1.0f, p1 = 1.0f;
#pragma unroll
                for (int u = 0; u < 8; ++u) {
                    float t0 = (m16b + u     < tripb) ? fmaf(swin[m16b + u],     invEb, 1.0f) : 1.0f;
                    float t1 = (m16b + 8 + u < tripb) ? fmaf(swin[m16b + 8 + u], invEb, 1.0f) : 1.0f;
                    p0 *= t0; p1 *= t1;
                }
                accL += __builtin_amdgcn_logf(p0) + __builtin_amdgcn_logf(p1);
            }
        }
        for (int off = 32; off > 0; off >>= 1) accL += __shfl_down(accL, off);
        if ((tid & 63) == 0) swave[tid >> 6] = accL;
        __syncthreads();
        if (tid == 0)
            g_part[row * NTILE + rank] = swave[0] + swave[1] + swave[2] + swave[3];
    }
}

__global__ __launch_bounds__(BLK) void rank_final(float* __restrict__ out) {
    double acc = 0.0;
    for (int idx = threadIdx.x; idx < TILEBLKS; idx += BLK) acc += (double)g_part[idx];
    for (int idx = threadIdx.x; idx < SIDEBLKS; idx += BLK) acc += g_partS[idx];
    for (int off = 32; off > 0; off >>= 1) acc += __shfl_down(acc, off);
    __shared__ double sw[4];
    if ((threadIdx.x & 63) == 0) sw[threadIdx.x >> 6] = acc;
    __syncthreads();
    if (threadIdx.x == 0)
        out[0] = (float)((sw[0] + sw[1] + sw[2] + sw[3]) *
                         (-0.6931471805599453 / (double)BB));
}

extern "C" void kernel_launch(void* const* d_in, const int* in_sizes, int n_in,
                              void* d_out, int out_size, void* d_ws, size_t ws_size,
                              hipStream_t stream) {
    const float* logits = (const float*)d_in[0];
    const float* labels = (const float*)d_in[1];
    float* out = (float*)d_out;
    (void)in_sizes; (void)n_in; (void)out_size; (void)d_ws; (void)ws_size;

    rank_pre<<<BB, BLK, 0, stream>>>(logits, labels);
    rank_work<<<WGRID, BLK, 0, stream>>>();
    rank_final<<<1, BLK, 0, stream>>>(out);
}